// Round 8
// baseline (361.300 us; speedup 1.0000x reference)
//
#include <hip/hip_runtime.h>
#include <hip/hip_bf16.h>

// ZeroPadder: out[b,t,0:1024] = x[b,t,:], out[b,t,1024:2048] = 0
// x: [16, 2048, 1024] f32 -> out: [16, 2048, 2048] f32 (32768 rows).
// Pure streaming copy+zero; 384 MiB traffic -> ~61 us @ 6.29 TB/s (m13 ceiling).
//
// Layout: block b owns 16 CONSECUTIVE output rows. Per row r, thread i:
//   out[r*512 + i]       = x[r*256 + i]   (i in [0,256): copy half)
//   out[r*512 + 256 + i] = 0              (zero half)
// => per block: x read = 64 KiB sequential, out write = 128 KiB sequential,
// each region written exactly once in address order (DRAM page locality,
// matching the access pattern of the 6.4 TB/s harness fills / m13 copy).
// Plain (non-NT) accesses: m13's 6.29 TB/s copy recipe. 16 loads hoisted
// up-front for memory-level parallelism (64 VGPRs of data).

typedef float f32x4 __attribute__((ext_vector_type(4)));

#define THREADS 256
#define ROWS_PER_BLOCK 16
#define BLOCKS (32768 / ROWS_PER_BLOCK)   // 2048 blocks = 8/CU

__global__ __launch_bounds__(THREADS) void ZeroPadder_19490561590035_kernel(
    const f32x4* __restrict__ x, f32x4* __restrict__ out) {
    const int i = threadIdx.x;
    const int xbase = blockIdx.x * (ROWS_PER_BLOCK * 256) + i;  // float4 index in x
    const int obase = blockIdx.x * (ROWS_PER_BLOCK * 512) + i;  // float4 index in out

    f32x4 v[ROWS_PER_BLOCK];
    #pragma unroll
    for (int r = 0; r < ROWS_PER_BLOCK; ++r)
        v[r] = x[xbase + r * 256];

    const f32x4 z = {0.f, 0.f, 0.f, 0.f};
    #pragma unroll
    for (int r = 0; r < ROWS_PER_BLOCK; ++r) {
        out[obase + r * 512]       = v[r];
        out[obase + r * 512 + 256] = z;
    }
}

extern "C" void kernel_launch(void* const* d_in, const int* in_sizes, int n_in,
                              void* d_out, int out_size, void* d_ws, size_t ws_size,
                              hipStream_t stream) {
    const f32x4* x = (const f32x4*)d_in[0];
    // d_in[1] (identity+zero weight) unused: the matmul is a pure zero-pad.
    f32x4* out = (f32x4*)d_out;
    ZeroPadder_19490561590035_kernel<<<BLOCKS, THREADS, 0, stream>>>(x, out);
}